// Round 10
// baseline (1680.402 us; speedup 1.0000x reference)
//
#include <hip/hip_runtime.h>
#include <hip/hip_fp16.h>
#include <math.h>

// GraphSAGE 2-layer, N=100000, E=3200000; IN=128, H1=32, H2=20, NCLS=10
// r10: bucket-direct aggregation (no CSR fill): k_part writes (src<<7|local)
// per 128-node dst bucket; agg kernels process one bucket per block with
// LDS f32 accumulators (ds_add_f32, bank=ch conflict-free) and 8-deep
// gather chunks (r7's MLP). lin1 LDS-staged for coalesced x reads.

#define BSHIFT 7
#define BS_NODES 128
#define PART_TILE 4096

__device__ __forceinline__ unsigned pk(float a, float b) {
    __half2 h = __floats2half2_rn(a, b);
    return *reinterpret_cast<unsigned*>(&h);
}

// ---- stage 0: init bucket cursors ----
__global__ __launch_bounds__(256) void k_binit(
    int* __restrict__ bcursor, int nb, int capb)
{
    int i = blockIdx.x * 256 + threadIdx.x;
    if (i < nb) bcursor[i] = i * capb;
}

// ---- stage 1: partition edges into per-bucket regions ----
__global__ __launch_bounds__(256) void k_part(
    const int* __restrict__ src, const int* __restrict__ dst,
    int* __restrict__ bcursor, int* __restrict__ pairs,
    int n_edges, int nb)
{
    __shared__ int cnt[1024];
    __shared__ int bbase_l[1024];
    int tid = threadIdx.x;
    int ebeg = blockIdx.x * PART_TILE;
    int eend = ebeg + PART_TILE; if (eend > n_edges) eend = n_edges;
    for (int i = tid; i < nb; i += 256) cnt[i] = 0;
    __syncthreads();
    for (int e = ebeg + tid; e < eend; e += 256)
        atomicAdd(&cnt[dst[e] >> BSHIFT], 1);
    __syncthreads();
    for (int i = tid; i < nb; i += 256) {
        int c = cnt[i];
        if (c > 0) bbase_l[i] = atomicAdd(&bcursor[i], c);
    }
    __syncthreads();
    for (int e = ebeg + tid; e < eend; e += 256) {
        int d = dst[e];
        int b = d >> BSHIFT;
        int slot = atomicSub(&cnt[b], 1) - 1;     // countdown ticket
        int v = (src[e] << BSHIFT) | (d & (BS_NODES - 1));
        __builtin_nontemporal_store(v, &pairs[(size_t)bbase_l[b] + slot]);
    }
}

// ---- lin1: LDS-staged (coalesced x), thread-per-node, fp16 outputs ----
// y1 = x@W1l (gather table), r1 = x@W1r + b1 (self path, bias folded)
__global__ __launch_bounds__(256) void k_lin1(
    const float* __restrict__ x, const float* __restrict__ W1l,
    const float* __restrict__ b1, const float* __restrict__ W1r,
    __half* __restrict__ y1, __half* __restrict__ r1, int n_nodes)
{
    __shared__ unsigned lds[256 * 64];   // 64KB: 256 rows x 128 halfs, rotated
    int tid = threadIdx.x;
    int base = blockIdx.x * 256;
    const float4* x4 = reinterpret_cast<const float4*>(x);
#pragma unroll
    for (int it = 0; it < 32; ++it) {
        int f = it * 256 + tid;
        int row = f >> 5, c4 = f & 31;
        int node = base + row;
        float4 v = make_float4(0.f, 0.f, 0.f, 0.f);
        if (node < n_nodes) v = x4[(size_t)node * 32 + c4];
        int kk = c4 * 2;
        lds[row * 64 + ((kk + row) & 63)]     = pk(v.x, v.y);
        lds[row * 64 + ((kk + 1 + row) & 63)] = pk(v.z, v.w);
    }
    __syncthreads();
    int node = base + tid;
    float accL[32], accR[32];
#pragma unroll
    for (int j = 0; j < 32; ++j) { accL[j] = 0.f; accR[j] = 0.f; }
    const unsigned* rb = &lds[tid * 64];
    for (int kk = 0; kk < 64; ++kk) {
        unsigned u = rb[(kk + tid) & 63];
        __half2 hh = *reinterpret_cast<__half2*>(&u);
        float2 f = __half22float2(hh);
        const float* wl = W1l + kk * 64;   // rows 2kk, 2kk+1 (wave-uniform)
        const float* wr = W1r + kk * 64;
#pragma unroll
        for (int j = 0; j < 32; ++j) {
            float a = accL[j];
            a = fmaf(f.x, wl[j],      a);
            a = fmaf(f.y, wl[32 + j], a);
            accL[j] = a;
            float c = accR[j];
            c = fmaf(f.x, wr[j],      c);
            c = fmaf(f.y, wr[32 + j], c);
            accR[j] = c;
        }
    }
    if (node < n_nodes) {
        unsigned o[16];
#pragma unroll
        for (int q = 0; q < 16; ++q) o[q] = pk(accL[2*q], accL[2*q+1]);
        uint4* yo = reinterpret_cast<uint4*>(y1 + (size_t)node * 32);
#pragma unroll
        for (int q = 0; q < 4; ++q)
            yo[q] = make_uint4(o[4*q], o[4*q+1], o[4*q+2], o[4*q+3]);
#pragma unroll
        for (int q = 0; q < 16; ++q)
            o[q] = pk(accR[2*q] + b1[2*q], accR[2*q+1] + b1[2*q+1]);
        uint4* ro = reinterpret_cast<uint4*>(r1 + (size_t)node * 32);
#pragma unroll
        for (int q = 0; q < 4; ++q)
            ro[q] = make_uint4(o[4*q], o[4*q+1], o[4*q+2], o[4*q+3]);
    }
}

// ---- Layer 1: one bucket per block; gather y1 -> LDS acc; epilogue
//      combine + normalize + relu + project (z2 = h@W2l, r2 = h@W2r + b2) ----
__global__ __launch_bounds__(256) void k_agg1(
    const int* __restrict__ bcursor, const int* __restrict__ pairs,
    const __half* __restrict__ y1, const __half* __restrict__ r1,
    const float* __restrict__ W2l, const float* __restrict__ W2r,
    const float* __restrict__ b2,
    __half* __restrict__ z2, __half* __restrict__ r2,
    float* __restrict__ degf, int capb, int n_nodes)
{
    __shared__ float acc[BS_NODES * 32];
    __shared__ int degl[BS_NODES];
    int b = blockIdx.x, tid = threadIdx.x;
    for (int i = tid; i < BS_NODES * 32; i += 256) acc[i] = 0.f;
    if (tid < BS_NODES) degl[tid] = 0;
    __syncthreads();
    int cntE = bcursor[b] - b * capb;
    const int* pp = pairs + (size_t)b * capb;
    int g = tid >> 5, ch = tid & 31;
    for (int bi = g * 8; bi < cntE; bi += 64) {
        int m = cntE - bi; if (m > 8) m = 8;
        if (m == 8) {
            int p0 = pp[bi],   p1 = pp[bi+1], p2 = pp[bi+2], p3 = pp[bi+3];
            int p4 = pp[bi+4], p5 = pp[bi+5], p6 = pp[bi+6], p7 = pp[bi+7];
            float v0 = __half2float(y1[(size_t)(p0 >> BSHIFT) * 32 + ch]);
            float v1 = __half2float(y1[(size_t)(p1 >> BSHIFT) * 32 + ch]);
            float v2 = __half2float(y1[(size_t)(p2 >> BSHIFT) * 32 + ch]);
            float v3 = __half2float(y1[(size_t)(p3 >> BSHIFT) * 32 + ch]);
            float v4 = __half2float(y1[(size_t)(p4 >> BSHIFT) * 32 + ch]);
            float v5 = __half2float(y1[(size_t)(p5 >> BSHIFT) * 32 + ch]);
            float v6 = __half2float(y1[(size_t)(p6 >> BSHIFT) * 32 + ch]);
            float v7 = __half2float(y1[(size_t)(p7 >> BSHIFT) * 32 + ch]);
            atomicAdd(&acc[(p0 & 127) * 32 + ch], v0);
            atomicAdd(&acc[(p1 & 127) * 32 + ch], v1);
            atomicAdd(&acc[(p2 & 127) * 32 + ch], v2);
            atomicAdd(&acc[(p3 & 127) * 32 + ch], v3);
            atomicAdd(&acc[(p4 & 127) * 32 + ch], v4);
            atomicAdd(&acc[(p5 & 127) * 32 + ch], v5);
            atomicAdd(&acc[(p6 & 127) * 32 + ch], v6);
            atomicAdd(&acc[(p7 & 127) * 32 + ch], v7);
            if (ch == 0) {
                atomicAdd(&degl[p0 & 127], 1);
                atomicAdd(&degl[p1 & 127], 1);
                atomicAdd(&degl[p2 & 127], 1);
                atomicAdd(&degl[p3 & 127], 1);
                atomicAdd(&degl[p4 & 127], 1);
                atomicAdd(&degl[p5 & 127], 1);
                atomicAdd(&degl[p6 & 127], 1);
                atomicAdd(&degl[p7 & 127], 1);
            }
        } else {
            for (int j = 0; j < m; ++j) {
                int p = pp[bi + j];
                float v = __half2float(y1[(size_t)(p >> BSHIFT) * 32 + ch]);
                atomicAdd(&acc[(p & 127) * 32 + ch], v);
                if (ch == 0) atomicAdd(&degl[p & 127], 1);
            }
        }
    }
    __syncthreads();
    for (int rr = 0; rr < 16; ++rr) {
        int local = g * 16 + rr;
        int node = b * BS_NODES + local;
        if (node >= n_nodes) break;
        float deg = (float)degl[local];
        float inv = 1.0f / fmaxf(deg, 1.0f);
        float v = fmaf(acc[local * 32 + ch], inv,
                       __half2float(r1[(size_t)node * 32 + ch]));
        float ss = v * v;
#pragma unroll
        for (int off = 16; off >= 1; off >>= 1) ss += __shfl_xor(ss, off, 32);
        float h = fmaxf(v / fmaxf(sqrtf(ss), 1e-12f), 0.f);
        float accl = 0.f, accr = 0.f;
#pragma unroll 4
        for (int ii = 0; ii < 32; ++ii) {
            float hv = __shfl(h, ii, 32);
            if (ch < 20) {
                accl = fmaf(hv, W2l[ii * 20 + ch], accl);
                accr = fmaf(hv, W2r[ii * 20 + ch], accr);
            }
        }
        z2[(size_t)node * 32 + ch] = __float2half(ch < 20 ? accl : 0.f);
        r2[(size_t)node * 32 + ch] = __float2half(ch < 20 ? accr + b2[ch] : 0.f);
        if (ch == 0) degf[node] = deg;
    }
}

// ---- Layer 2: one bucket per block; gather z2 -> LDS acc; epilogue
//      combine + normalize + W_out + softmax ----
__global__ __launch_bounds__(256) void k_agg2(
    const int* __restrict__ bcursor, const int* __restrict__ pairs,
    const __half* __restrict__ z2, const __half* __restrict__ r2,
    const float* __restrict__ degf, const float* __restrict__ Wout,
    const float* __restrict__ bout, float* __restrict__ out,
    int capb, int n_nodes)
{
    __shared__ float acc[BS_NODES * 32];
    int b = blockIdx.x, tid = threadIdx.x;
    for (int i = tid; i < BS_NODES * 32; i += 256) acc[i] = 0.f;
    __syncthreads();
    int cntE = bcursor[b] - b * capb;
    const int* pp = pairs + (size_t)b * capb;
    int g = tid >> 5, ch = tid & 31;
    for (int bi = g * 8; bi < cntE; bi += 64) {
        int m = cntE - bi; if (m > 8) m = 8;
        if (m == 8) {
            int p0 = pp[bi],   p1 = pp[bi+1], p2 = pp[bi+2], p3 = pp[bi+3];
            int p4 = pp[bi+4], p5 = pp[bi+5], p6 = pp[bi+6], p7 = pp[bi+7];
            float v0 = __half2float(z2[(size_t)(p0 >> BSHIFT) * 32 + ch]);
            float v1 = __half2float(z2[(size_t)(p1 >> BSHIFT) * 32 + ch]);
            float v2 = __half2float(z2[(size_t)(p2 >> BSHIFT) * 32 + ch]);
            float v3 = __half2float(z2[(size_t)(p3 >> BSHIFT) * 32 + ch]);
            float v4 = __half2float(z2[(size_t)(p4 >> BSHIFT) * 32 + ch]);
            float v5 = __half2float(z2[(size_t)(p5 >> BSHIFT) * 32 + ch]);
            float v6 = __half2float(z2[(size_t)(p6 >> BSHIFT) * 32 + ch]);
            float v7 = __half2float(z2[(size_t)(p7 >> BSHIFT) * 32 + ch]);
            atomicAdd(&acc[(p0 & 127) * 32 + ch], v0);
            atomicAdd(&acc[(p1 & 127) * 32 + ch], v1);
            atomicAdd(&acc[(p2 & 127) * 32 + ch], v2);
            atomicAdd(&acc[(p3 & 127) * 32 + ch], v3);
            atomicAdd(&acc[(p4 & 127) * 32 + ch], v4);
            atomicAdd(&acc[(p5 & 127) * 32 + ch], v5);
            atomicAdd(&acc[(p6 & 127) * 32 + ch], v6);
            atomicAdd(&acc[(p7 & 127) * 32 + ch], v7);
        } else {
            for (int j = 0; j < m; ++j) {
                int p = pp[bi + j];
                float v = __half2float(z2[(size_t)(p >> BSHIFT) * 32 + ch]);
                atomicAdd(&acc[(p & 127) * 32 + ch], v);
            }
        }
    }
    __syncthreads();
    for (int rr = 0; rr < 16; ++rr) {
        int local = g * 16 + rr;
        int node = b * BS_NODES + local;
        if (node >= n_nodes) break;
        float deg = degf[node];
        float inv = 1.0f / fmaxf(deg, 1.0f);
        float v = 0.f;
        if (ch < 20)
            v = fmaf(acc[local * 32 + ch], inv,
                     __half2float(r2[(size_t)node * 32 + ch]));
        float ss = v * v;
#pragma unroll
        for (int off = 16; off >= 1; off >>= 1) ss += __shfl_xor(ss, off, 32);
        float innrm = 1.0f / fmaxf(sqrtf(ss), 1e-12f);
        float o = v * innrm;
        float lacc = (ch < 10) ? bout[ch] : 0.f;
#pragma unroll 4
        for (int ii = 0; ii < 20; ++ii) {
            float ov = __shfl(o, ii, 32);
            if (ch < 10) lacc = fmaf(ov, Wout[ii * 10 + ch], lacc);
        }
        float lm = (ch < 10) ? lacc : -1e30f;
#pragma unroll
        for (int off = 8; off >= 1; off >>= 1) lm = fmaxf(lm, __shfl_xor(lm, off, 16));
        float ex = (ch < 10) ? expf(lacc - lm) : 0.f;
        float es = ex;
#pragma unroll
        for (int off = 8; off >= 1; off >>= 1) es += __shfl_xor(es, off, 16);
        if (ch < 10) out[(size_t)node * 10 + ch] = ex / es;
    }
}

extern "C" void kernel_launch(void* const* d_in, const int* in_sizes, int n_in,
                              void* d_out, int out_size, void* d_ws, size_t ws_size,
                              hipStream_t stream)
{
    const float* x    = (const float*)d_in[0];
    const int*   ei   = (const int*)d_in[1];
    const float* W1l  = (const float*)d_in[2];
    const float* b1   = (const float*)d_in[3];
    const float* W1r  = (const float*)d_in[4];
    const float* W2l  = (const float*)d_in[5];
    const float* b2   = (const float*)d_in[6];
    const float* W2r  = (const float*)d_in[7];
    const float* Wout = (const float*)d_in[8];
    const float* bout = (const float*)d_in[9];
    float* out = (float*)d_out;

    int n_nodes = in_sizes[0] / 128;
    int n_edges = in_sizes[1] / 2;
    const int* src = ei;
    const int* dst = ei + n_edges;

    int nb = (n_nodes + BS_NODES - 1) / BS_NODES;   // 782 (<= 1024)
    double mean = (double)n_edges / nb;
    int capb = (int)(mean + 8.0 * sqrt(mean) + 64.0);
    capb = (capb + 63) & ~63;

    // workspace: bcursor | pairs | y1 | r1 | z2 | r2 | degf
    int* bcursor = (int*)d_ws;                       // nb
    int* pairs   = bcursor + ((nb + 3) & ~3);        // nb*capb
    size_t npairs = ((size_t)nb * capb + 3) & ~(size_t)3;
    __half* y1 = (__half*)(pairs + npairs);          // N*32 halfs (64B rows)
    __half* r1 = y1 + (size_t)n_nodes * 32;          // N*32 halfs (b1 folded)
    __half* z2 = r1 + (size_t)n_nodes * 32;          // N*32 halfs (20 used)
    __half* r2 = z2 + (size_t)n_nodes * 32;          // N*32 halfs (b2 folded)
    float* degf = (float*)(r2 + (size_t)n_nodes * 32); // N f32

    k_binit<<<(nb + 255) / 256, 256, 0, stream>>>(bcursor, nb, capb);
    k_part<<<(n_edges + PART_TILE - 1) / PART_TILE, 256, 0, stream>>>(
        src, dst, bcursor, pairs, n_edges, nb);
    k_lin1<<<(n_nodes + 255) / 256, 256, 0, stream>>>(
        x, W1l, b1, W1r, y1, r1, n_nodes);
    k_agg1<<<nb, 256, 0, stream>>>(bcursor, pairs, y1, r1, W2l, W2r, b2,
                                   z2, r2, degf, capb, n_nodes);
    k_agg2<<<nb, 256, 0, stream>>>(bcursor, pairs, z2, r2, degf, Wout, bout,
                                   out, capb, n_nodes);
}

// Round 11
// 322.833 us; speedup vs baseline: 5.2052x; 5.2052x over previous
//
#include <hip/hip_runtime.h>
#include <hip/hip_fp16.h>
#include <math.h>

// GraphSAGE 2-layer, N=100000, E=3200000; IN=128, H1=32, H2=20, NCLS=10
// r11 = r7 structure (node-parallel gather agg, CSR via 2-level bucketing)
//     + r10's validated LDS-staged lin1 (coalesced x) and fp16 r1/r2
//       (biases folded). r10's bucket-direct agg reverted (parallelism
//       collapse: 782 blocks, 28% occupancy, 143 GB/s).

#define BSHIFT 7
#define BS_NODES 128
#define PART_TILE 8192

__device__ __forceinline__ unsigned pk(float a, float b) {
    __half2 h = __floats2half2_rn(a, b);
    return *reinterpret_cast<unsigned*>(&h);
}

// ---- CSR build, stage 0 ----
__global__ __launch_bounds__(256) void k_binit(
    int* __restrict__ bcursor, int nb, int capb)
{
    int i = blockIdx.x * 256 + threadIdx.x;
    if (i < nb) bcursor[i] = i * capb;
}

// ---- stage 1: partition edges into per-bucket regions ----
__global__ __launch_bounds__(256) void k_part(
    const int* __restrict__ src, const int* __restrict__ dst,
    int* __restrict__ bcursor, int* __restrict__ pairs,
    int n_edges, int nb)
{
    __shared__ int cnt[1024];
    __shared__ int bbase_l[1024];
    int tid = threadIdx.x;
    int ebeg = blockIdx.x * PART_TILE;
    int eend = ebeg + PART_TILE; if (eend > n_edges) eend = n_edges;
    for (int i = tid; i < nb; i += 256) cnt[i] = 0;
    __syncthreads();
    for (int e = ebeg + tid; e < eend; e += 256)
        atomicAdd(&cnt[dst[e] >> BSHIFT], 1);
    __syncthreads();
    for (int i = tid; i < nb; i += 256) {
        int c = cnt[i];
        if (c > 0) bbase_l[i] = atomicAdd(&bcursor[i], c);
    }
    __syncthreads();
    for (int e = ebeg + tid; e < eend; e += 256) {
        int d = dst[e];
        int b = d >> BSHIFT;
        int slot = atomicSub(&cnt[b], 1) - 1;     // countdown ticket
        pairs[(size_t)bbase_l[b] + slot] = (src[e] << BSHIFT) | (d & (BS_NODES - 1));
    }
}

// ---- stage 2: scan bucket counts ----
__global__ __launch_bounds__(1024) void k_bscan(
    const int* __restrict__ bcursor, int* __restrict__ bbase,
    int* __restrict__ row_ptr, int nb, int capb, int n_nodes)
{
    __shared__ int sc[1024];
    int t = threadIdx.x;
    int c = (t < nb) ? (bcursor[t] - t * capb) : 0;
    sc[t] = c;
    __syncthreads();
    for (int off = 1; off < 1024; off <<= 1) {
        int v = (t >= off) ? sc[t - off] : 0;
        __syncthreads();
        sc[t] += v;
        __syncthreads();
    }
    if (t < nb) bbase[t] = sc[t] - c;   // exclusive
    if (t == 1023) row_ptr[n_nodes] = sc[t];
}

// ---- stage 3: per-bucket fill of row_ptr + eid ----
__global__ __launch_bounds__(256) void k_bfill(
    const int* __restrict__ pairs, const int* __restrict__ bcursor,
    const int* __restrict__ bbase, int* __restrict__ row_ptr,
    int* __restrict__ eid, int capb, int n_nodes)
{
    __shared__ int cnt128[BS_NODES];
    __shared__ int sc[BS_NODES];
    __shared__ int cur[BS_NODES];
    int b = blockIdx.x;
    int t = threadIdx.x;
    int lo = b * BS_NODES;
    size_t pbeg = (size_t)b * capb;
    int cntE = bcursor[b] - b * capb;
    int base = bbase[b];
    if (t < BS_NODES) cnt128[t] = 0;
    __syncthreads();
    for (int i = t; i < cntE; i += 256)
        atomicAdd(&cnt128[pairs[pbeg + i] & (BS_NODES - 1)], 1);
    __syncthreads();
    int myc = 0;
    if (t < BS_NODES) { myc = cnt128[t]; sc[t] = myc; }
    __syncthreads();
    for (int off = 1; off < BS_NODES; off <<= 1) {
        int v = (t >= off && t < BS_NODES) ? sc[t - off] : 0;
        __syncthreads();
        if (t < BS_NODES) sc[t] += v;
        __syncthreads();
    }
    if (t < BS_NODES) {
        int excl = sc[t] - myc;
        cur[t] = excl;
        if (lo + t < n_nodes) row_ptr[lo + t] = base + excl;
    }
    __syncthreads();
    for (int i = t; i < cntE; i += 256) {
        int p = pairs[pbeg + i];
        int pos = atomicAdd(&cur[p & (BS_NODES - 1)], 1);
        eid[(size_t)base + pos] = p >> BSHIFT;
    }
}

// ---- lin1: LDS-staged (coalesced x), thread-per-node, fp16 outputs ----
// y1 = x@W1l (gather table), r1 = x@W1r + b1 (self path, bias folded)
__global__ __launch_bounds__(256) void k_lin1(
    const float* __restrict__ x, const float* __restrict__ W1l,
    const float* __restrict__ b1, const float* __restrict__ W1r,
    __half* __restrict__ y1, __half* __restrict__ r1, int n_nodes)
{
    __shared__ unsigned lds[256 * 64];   // 64KB: 256 rows x 128 halfs, rotated
    int tid = threadIdx.x;
    int base = blockIdx.x * 256;
    const float4* x4 = reinterpret_cast<const float4*>(x);
#pragma unroll
    for (int it = 0; it < 32; ++it) {
        int f = it * 256 + tid;
        int row = f >> 5, c4 = f & 31;
        int node = base + row;
        float4 v = make_float4(0.f, 0.f, 0.f, 0.f);
        if (node < n_nodes) v = x4[(size_t)node * 32 + c4];
        int kk = c4 * 2;
        lds[row * 64 + ((kk + row) & 63)]     = pk(v.x, v.y);
        lds[row * 64 + ((kk + 1 + row) & 63)] = pk(v.z, v.w);
    }
    __syncthreads();
    int node = base + tid;
    float accL[32], accR[32];
#pragma unroll
    for (int j = 0; j < 32; ++j) { accL[j] = 0.f; accR[j] = 0.f; }
    const unsigned* rb = &lds[tid * 64];
    for (int kk = 0; kk < 64; ++kk) {
        unsigned u = rb[(kk + tid) & 63];
        __half2 hh = *reinterpret_cast<__half2*>(&u);
        float2 f = __half22float2(hh);
        const float* wl = W1l + kk * 64;   // rows 2kk, 2kk+1 (wave-uniform)
        const float* wr = W1r + kk * 64;
#pragma unroll
        for (int j = 0; j < 32; ++j) {
            float a = accL[j];
            a = fmaf(f.x, wl[j],      a);
            a = fmaf(f.y, wl[32 + j], a);
            accL[j] = a;
            float c = accR[j];
            c = fmaf(f.x, wr[j],      c);
            c = fmaf(f.y, wr[32 + j], c);
            accR[j] = c;
        }
    }
    if (node < n_nodes) {
        unsigned o[16];
#pragma unroll
        for (int q = 0; q < 16; ++q) o[q] = pk(accL[2*q], accL[2*q+1]);
        uint4* yo = reinterpret_cast<uint4*>(y1 + (size_t)node * 32);
#pragma unroll
        for (int q = 0; q < 4; ++q)
            yo[q] = make_uint4(o[4*q], o[4*q+1], o[4*q+2], o[4*q+3]);
#pragma unroll
        for (int q = 0; q < 16; ++q)
            o[q] = pk(accR[2*q] + b1[2*q], accR[2*q+1] + b1[2*q+1]);
        uint4* ro = reinterpret_cast<uint4*>(r1 + (size_t)node * 32);
#pragma unroll
        for (int q = 0; q < 4; ++q)
            ro[q] = make_uint4(o[4*q], o[4*q+1], o[4*q+2], o[4*q+3]);
    }
}

// ---- gather-sum over [beg,end): 8 independent chains, cached eid loads ----
__device__ __forceinline__ float gather_sum(
    const int* __restrict__ eid, const __half* __restrict__ tab,
    int beg, int end, int ch)
{
    float s0 = 0.f, s1 = 0.f, s2 = 0.f, s3 = 0.f;
    float s4 = 0.f, s5 = 0.f, s6 = 0.f, s7 = 0.f;
    int i = beg;
    for (; i + 8 <= end; i += 8) {
        int e0 = eid[i];
        int e1 = eid[i + 1];
        int e2 = eid[i + 2];
        int e3 = eid[i + 3];
        int e4 = eid[i + 4];
        int e5 = eid[i + 5];
        int e6 = eid[i + 6];
        int e7 = eid[i + 7];
        s0 += __half2float(tab[(size_t)e0 * 32 + ch]);
        s1 += __half2float(tab[(size_t)e1 * 32 + ch]);
        s2 += __half2float(tab[(size_t)e2 * 32 + ch]);
        s3 += __half2float(tab[(size_t)e3 * 32 + ch]);
        s4 += __half2float(tab[(size_t)e4 * 32 + ch]);
        s5 += __half2float(tab[(size_t)e5 * 32 + ch]);
        s6 += __half2float(tab[(size_t)e6 * 32 + ch]);
        s7 += __half2float(tab[(size_t)e7 * 32 + ch]);
    }
    for (; i + 4 <= end; i += 4) {
        int e0 = eid[i];
        int e1 = eid[i + 1];
        int e2 = eid[i + 2];
        int e3 = eid[i + 3];
        s0 += __half2float(tab[(size_t)e0 * 32 + ch]);
        s1 += __half2float(tab[(size_t)e1 * 32 + ch]);
        s2 += __half2float(tab[(size_t)e2 * 32 + ch]);
        s3 += __half2float(tab[(size_t)e3 * 32 + ch]);
    }
    for (; i < end; ++i) {
        int e = eid[i];
        s0 += __half2float(tab[(size_t)e * 32 + ch]);
    }
    return ((s0 + s1) + (s2 + s3)) + ((s4 + s5) + (s6 + s7));
}

// ---- Layer 1: gather-sum y1, combine (fp16 r1, b1 folded), norm, relu,
//      project -> z2 fp16, r2 fp16 (b2 folded) ----
__global__ __launch_bounds__(256) void k_agg1(
    const int* __restrict__ row_ptr, const int* __restrict__ eid,
    const __half* __restrict__ y1, const __half* __restrict__ r1,
    const float* __restrict__ W2l, const float* __restrict__ W2r,
    const float* __restrict__ b2,
    __half* __restrict__ z2, __half* __restrict__ r2, int n_nodes)
{
    int t = blockIdx.x * 256 + threadIdx.x;
    int n = t >> 5;
    int ch = t & 31;
    if (n >= n_nodes) return;
    int beg = row_ptr[n], end = row_ptr[n + 1];
    float sum = gather_sum(eid, y1, beg, end, ch);
    float inv = 1.0f / fmaxf((float)(end - beg), 1.0f);
    float v = fmaf(sum, inv, __half2float(r1[(size_t)n * 32 + ch]));
    float ss = v * v;
#pragma unroll
    for (int off = 16; off >= 1; off >>= 1) ss += __shfl_xor(ss, off, 32);
    float h = fmaxf(v / fmaxf(sqrtf(ss), 1e-12f), 0.f);
    float accl = 0.f, accr = 0.f;
#pragma unroll 4
    for (int ii = 0; ii < 32; ++ii) {
        float hv = __shfl(h, ii, 32);
        if (ch < 20) {
            accl = fmaf(hv, W2l[ii * 20 + ch], accl);
            accr = fmaf(hv, W2r[ii * 20 + ch], accr);
        }
    }
    z2[(size_t)n * 32 + ch] = __float2half(ch < 20 ? accl : 0.f);
    r2[(size_t)n * 32 + ch] = __float2half(ch < 20 ? accr + b2[ch] : 0.f);
}

// ---- Layer 2: gather-sum z2, combine (fp16 r2, b2 folded), norm,
//      W_out, softmax ----
__global__ __launch_bounds__(256) void k_agg2(
    const int* __restrict__ row_ptr, const int* __restrict__ eid,
    const __half* __restrict__ z2, const __half* __restrict__ r2,
    const float* __restrict__ Wout, const float* __restrict__ bout,
    float* __restrict__ out, int n_nodes)
{
    int t = blockIdx.x * 256 + threadIdx.x;
    int n = t >> 5;
    int ch = t & 31;
    if (n >= n_nodes) return;
    int beg = row_ptr[n], end = row_ptr[n + 1];
    bool act = ch < 20;
    float sum = gather_sum(eid, z2, beg, end, ch);
    float inv = 1.0f / fmaxf((float)(end - beg), 1.0f);
    float v = act ? fmaf(sum, inv, __half2float(r2[(size_t)n * 32 + ch])) : 0.f;
    float ss = v * v;
#pragma unroll
    for (int off = 16; off >= 1; off >>= 1) ss += __shfl_xor(ss, off, 32);
    float o = v / fmaxf(sqrtf(ss), 1e-12f);
    float acc = (ch < 10) ? bout[ch] : 0.f;
#pragma unroll 4
    for (int ii = 0; ii < 20; ++ii) {
        float ov = __shfl(o, ii, 32);
        if (ch < 10) acc = fmaf(ov, Wout[ii * 10 + ch], acc);
    }
    float lm = (ch < 10) ? acc : -1e30f;
    float m = lm;
#pragma unroll
    for (int off = 8; off >= 1; off >>= 1) m = fmaxf(m, __shfl_xor(m, off, 16));
    float ex = (ch < 10) ? expf(acc - m) : 0.f;
    float s2r = ex;
#pragma unroll
    for (int off = 8; off >= 1; off >>= 1) s2r += __shfl_xor(s2r, off, 16);
    if (ch < 10) out[(size_t)n * 10 + ch] = ex / s2r;
}

extern "C" void kernel_launch(void* const* d_in, const int* in_sizes, int n_in,
                              void* d_out, int out_size, void* d_ws, size_t ws_size,
                              hipStream_t stream)
{
    const float* x    = (const float*)d_in[0];
    const int*   ei   = (const int*)d_in[1];
    const float* W1l  = (const float*)d_in[2];
    const float* b1   = (const float*)d_in[3];
    const float* W1r  = (const float*)d_in[4];
    const float* W2l  = (const float*)d_in[5];
    const float* b2   = (const float*)d_in[6];
    const float* W2r  = (const float*)d_in[7];
    const float* Wout = (const float*)d_in[8];
    const float* bout = (const float*)d_in[9];
    float* out = (float*)d_out;

    int n_nodes = in_sizes[0] / 128;
    int n_edges = in_sizes[1] / 2;
    const int* src = ei;
    const int* dst = ei + n_edges;

    int nb = (n_nodes + BS_NODES - 1) / BS_NODES;   // 782 (<= 1024)
    double mean = (double)n_edges / nb;
    int capb = (int)(mean + 8.0 * sqrt(mean) + 64.0);
    capb = (capb + 63) & ~63;

    // workspace layout
    int* bcursor = (int*)d_ws;                          // nb
    int* bbase   = bcursor + ((nb + 2 + 3) & ~3);       // nb
    int* row_ptr = bbase + ((nb + 3) & ~3);             // n_nodes+1
    int* eid     = row_ptr + (((n_nodes + 1) + 3) & ~3);// n_edges
    int* pairs   = eid + (((size_t)n_edges + 3) & ~(size_t)3);  // nb*capb

    // fp16 tables; y1 aliases pairs (pairs dead before k_lin1 runs)
    __half* y1 = (__half*)pairs;                        // N*32 halfs (64B rows)
    __half* r1 = y1 + (size_t)n_nodes * 32;             // N*32 halfs (b1 folded)
    __half* z2 = r1 + (size_t)n_nodes * 32;             // N*32 halfs (20 used)
    __half* r2 = z2 + (size_t)n_nodes * 32;             // N*32 halfs (b2 folded)

    int nb_part = (n_edges + PART_TILE - 1) / PART_TILE;
    int nb_node = (n_nodes + 255) / 256;
    int nb_grp  = ((n_nodes * 32) + 255) / 256;

    k_binit<<<(nb + 255) / 256, 256, 0, stream>>>(bcursor, nb, capb);
    k_part<<<nb_part, 256, 0, stream>>>(src, dst, bcursor, pairs, n_edges, nb);
    k_bscan<<<1, 1024, 0, stream>>>(bcursor, bbase, row_ptr, nb, capb, n_nodes);
    k_bfill<<<nb, 256, 0, stream>>>(pairs, bcursor, bbase, row_ptr, eid, capb, n_nodes);
    k_lin1<<<nb_node, 256, 0, stream>>>(x, W1l, b1, W1r, y1, r1, n_nodes);
    k_agg1<<<nb_grp, 256, 0, stream>>>(row_ptr, eid, y1, r1, W2l, W2r, b2, z2, r2, n_nodes);
    k_agg2<<<nb_grp, 256, 0, stream>>>(row_ptr, eid, z2, r2, Wout, bout, out, n_nodes);
}